// Round 4
// baseline (523.982 us; speedup 1.0000x reference)
//
#include <hip/hip_runtime.h>
#include <hip/hip_bf16.h>

#define HW 4096
#define CC 256
#define NBATCH 8
#define EPSF 1e-6f

typedef __attribute__((ext_vector_type(8))) short short8;
typedef __attribute__((ext_vector_type(4))) float floatx4;

// monotone float <-> unsigned key (order-preserving)
__device__ __forceinline__ unsigned fkey(float f){
    unsigned u = __float_as_uint(f);
    return (u & 0x80000000u) ? ~u : (u | 0x80000000u);
}
__device__ __forceinline__ float fdec(unsigned k){
    unsigned u = (k & 0x80000000u) ? (k ^ 0x80000000u) : ~k;
    return __uint_as_float(u);
}
__device__ __forceinline__ unsigned short f2bf(float f){
    unsigned u = __float_as_uint(f);
    u += 0x7FFFu + ((u >> 16) & 1);
    return (unsigned short)(u >> 16);
}

// ---------------- kernel 1: per-channel mean of y ----------------
__global__ __launch_bounds__(256) void kmean(const float* __restrict__ y,
                                             float* __restrict__ ymu){
    const int c = blockIdx.x;
    const int t = threadIdx.x;
    float s = 0.f;
    for(int n = 0; n < NBATCH; n++){
        const float* p = y + ((size_t)n*CC + c)*HW;
        for(int i = t; i < HW; i += 256) s += p[i];
    }
    __shared__ float red[256];
    red[t] = s; __syncthreads();
    for(int off = 128; off > 0; off >>= 1){
        if(t < off) red[t] += red[t+off];
        __syncthreads();
    }
    if(t == 0) ymu[c] = red[0] * (1.0f/((float)NBATCH*HW));
}

// ---- kernel 2: center, normalize over C, emit MFMA-fragment-major bf16 ----
// layout per batch: elem(i, c) at  (i>>4)*4096 + kt*512 + q*128 + (i&15)*8 + e
//   where c = kt*32 + q*8 + e.  So a fragment load is base + lane*16B.
// Also initializes colmaxk (folded former kinit).
#define TROW 264
__global__ __launch_bounds__(256) void knorm(const float* __restrict__ x,
                                             const float* __restrict__ y,
                                             const float* __restrict__ ymu,
                                             unsigned short* __restrict__ xF,
                                             unsigned short* __restrict__ yF,
                                             unsigned* __restrict__ colmaxk){
    __shared__ __align__(16) unsigned short tile[64*TROW];
    __shared__ float invn[64];
    __shared__ float partial[4][64];
    __shared__ float smu[CC];
    const int t   = threadIdx.x;
    const int hw0 = blockIdx.x * 64;
    const int n   = blockIdx.y;
    if(t < 64) colmaxk[(size_t)n*HW + hw0 + t] = 0u;
    for(int c = t; c < CC; c += 256) smu[c] = ymu[c];
    const int hwl = t & 63;
    const int cch = t >> 6;
    for(int which = 0; which < 2; which++){
        const float* __restrict__ src = which ? y : x;
        unsigned short* __restrict__ dst = which ? yF : xF;
        __syncthreads();
        float ss = 0.f;
        for(int cc = 0; cc < 64; cc++){
            int c = cch*64 + cc;
            float v = src[((size_t)n*CC + c)*HW + hw0 + hwl] - smu[c];
            ss += v*v;
            tile[hwl*TROW + c] = f2bf(v);
        }
        partial[cch][hwl] = ss;
        __syncthreads();
        if(t < 64){
            float s = partial[0][t]+partial[1][t]+partial[2][t]+partial[3][t];
            invn[t] = rsqrtf(s);
        }
        __syncthreads();
        size_t base = (size_t)n*HW*CC + (size_t)(hw0 >> 4)*4096;
        #pragma unroll
        for(int v8 = 0; v8 < 8; v8++){
            int g   = v8*256 + t;          // 0..2047, unit = 8 halves
            int lit = g >> 9;
            int kt  = (g >> 6) & 7;
            int qq  = (g >> 4) & 3;
            int ll  = g & 15;
            int hr  = lit*16 + ll;
            float inv = invn[hr];
            const unsigned* lp = reinterpret_cast<const unsigned*>(&tile[hr*TROW + kt*32 + qq*8]);
            unsigned o[4];
            #pragma unroll
            for(int w2 = 0; w2 < 4; w2++){
                unsigned uu = lp[w2];
                float f0 = __uint_as_float((uu & 0xFFFFu) << 16) * inv;
                float f1 = __uint_as_float(uu & 0xFFFF0000u) * inv;
                o[w2] = (unsigned)f2bf(f0) | ((unsigned)f2bf(f1) << 16);
            }
            uint4 ov; ov.x=o[0]; ov.y=o[1]; ov.z=o[2]; ov.w=o[3];
            *reinterpret_cast<uint4*>(dst + base + (size_t)g*8) = ov;
        }
    }
}

// ---- pipelined sweep: flattened m = js*8+kt, prefetch distance 2 ----
// Yn is pre-offset by wave*4*4096 + lane*8. yF must have >=512KB slack after
// each batch's region is fine globally (tail prefetch reads garbage, unused).
template<class EPI>
__device__ __forceinline__ void sweep(const unsigned short* __restrict__ Yn,
                                      const short8 af[4][8], EPI&& epi){
    short8 b[2][4];
    const unsigned short* Bw = Yn;
    #pragma unroll
    for(int tj = 0; tj < 4; tj++)
        b[0][tj] = *reinterpret_cast<const short8*>(Bw + tj*4096);
    #pragma unroll
    for(int tj = 0; tj < 4; tj++)
        b[1][tj] = *reinterpret_cast<const short8*>(Bw + tj*4096 + 512);
    #pragma unroll 1
    for(int js = 0; js < 16; js++, Bw += 65536){
        floatx4 acc[4][4];
        #pragma unroll
        for(int a = 0; a < 4; a++)
            #pragma unroll
            for(int c = 0; c < 4; c++) acc[a][c] = (floatx4){0.f,0.f,0.f,0.f};
        #pragma unroll
        for(int kt = 0; kt < 8; kt++){
            const unsigned short* pn = Bw + ((kt+2) >> 3)*65536 + ((kt+2) & 7)*512;
            #pragma unroll
            for(int tj = 0; tj < 4; tj++){
                #pragma unroll
                for(int ti = 0; ti < 4; ti++)
                    acc[ti][tj] = __builtin_amdgcn_mfma_f32_16x16x32_bf16(
                                      af[ti][kt], b[kt&1][tj], acc[ti][tj], 0, 0, 0);
                b[kt&1][tj] = *reinterpret_cast<const short8*>(pn + tj*4096);
            }
        }
        epi(js, acc);
    }
}

// ---- fused 3-sweep kernel: block = 64-row i-panel, A in registers ----
__global__ __launch_bounds__(256, 2) void kccx(const unsigned short* __restrict__ xF,
                                               const unsigned short* __restrict__ yF,
                                               unsigned* __restrict__ colmaxk){
    __shared__ unsigned dminU[64];
    __shared__ float    rsF[64];
    const int t    = threadIdx.x;
    const int lane = t & 63;
    const int wave = t >> 6;
    const int q    = lane >> 4;
    const int l15  = lane & 15;
    const int bid  = blockIdx.x;
    const int n    = bid & 7;          // batch <-> XCD affinity (L2 locality)
    const int ip   = bid >> 3;         // i-panel 0..63
    const size_t nbase = (size_t)n*HW*CC;
    const unsigned short* Ax = xF + nbase + (size_t)ip*16384;
    const unsigned short* Yn = yF + nbase + (size_t)wave*4*4096 + lane*8;
    if(t < 64){ dminU[t] = 0xFFFFFFFFu; rsF[t] = 0.f; }
    __syncthreads();

    short8 af[4][8];
    #pragma unroll
    for(int ti = 0; ti < 4; ti++)
        #pragma unroll
        for(int kt = 0; kt < 8; kt++)
            af[ti][kt] = *reinterpret_cast<const short8*>(Ax + ti*4096 + kt*512 + lane*8);

    // ---- sweep 1: d_min per row (block-local) ----
    float rmax[4][4];
    #pragma unroll
    for(int ti = 0; ti < 4; ti++)
        #pragma unroll
        for(int r = 0; r < 4; r++) rmax[ti][r] = -3e38f;
    sweep(Yn, af, [&](int js, floatx4 (&acc)[4][4]){
        #pragma unroll
        for(int ti = 0; ti < 4; ti++)
            #pragma unroll
            for(int r = 0; r < 4; r++){
                float v = fmaxf(fmaxf(acc[ti][0][r], acc[ti][1][r]),
                                fmaxf(acc[ti][2][r], acc[ti][3][r]));
                v = fmaxf(v, __shfl_xor(v, 1));
                v = fmaxf(v, __shfl_xor(v, 2));
                v = fmaxf(v, __shfl_xor(v, 4));
                v = fmaxf(v, __shfl_xor(v, 8));
                rmax[ti][r] = fmaxf(rmax[ti][r], v);
            }
    });
    #pragma unroll
    for(int ti = 0; ti < 4; ti++)
        #pragma unroll
        for(int r = 0; r < 4; r++)
            if(l15 == 0) atomicMin(&dminU[ti*16 + q*4 + r], fkey(1.f - rmax[ti][r]));
    __syncthreads();
    float sc[4][4];
    #pragma unroll
    for(int ti = 0; ti < 4; ti++)
        #pragma unroll
        for(int r = 0; r < 4; r++)
            sc[ti][r] = 2.f / (fdec(dminU[ti*16 + q*4 + r]) + EPSF);

    // ---- sweep 2: rowsum of w (block-local) ----
    float rsum[4][4];
    #pragma unroll
    for(int ti = 0; ti < 4; ti++)
        #pragma unroll
        for(int r = 0; r < 4; r++) rsum[ti][r] = 0.f;
    sweep(Yn, af, [&](int js, floatx4 (&acc)[4][4]){
        #pragma unroll
        for(int ti = 0; ti < 4; ti++)
            #pragma unroll
            for(int r = 0; r < 4; r++){
                float s_ = sc[ti][r];
                float c2 = 2.f - s_;
                float v = __expf(fmaf(acc[ti][0][r], s_, c2))
                        + __expf(fmaf(acc[ti][1][r], s_, c2))
                        + __expf(fmaf(acc[ti][2][r], s_, c2))
                        + __expf(fmaf(acc[ti][3][r], s_, c2));
                v += __shfl_xor(v, 1);
                v += __shfl_xor(v, 2);
                v += __shfl_xor(v, 4);
                v += __shfl_xor(v, 8);
                rsum[ti][r] += v;
            }
    });
    #pragma unroll
    for(int ti = 0; ti < 4; ti++)
        #pragma unroll
        for(int r = 0; r < 4; r++)
            if(l15 == 0) atomicAdd(&rsF[ti*16 + q*4 + r], rsum[ti][r]);
    __syncthreads();
    float bb[4][4];
    #pragma unroll
    for(int ti = 0; ti < 4; ti++)
        #pragma unroll
        for(int r = 0; r < 4; r++)
            bb[ti][r] = 2.f - sc[ti][r] - __logf(rsF[ti*16 + q*4 + r]);

    // ---- sweep 3: colmax of ccx (global atomics, batch-local words) ----
    sweep(Yn, af, [&](int js, floatx4 (&acc)[4][4]){
        #pragma unroll
        for(int tj = 0; tj < 4; tj++){
            float v = 0.f;
            #pragma unroll
            for(int ti = 0; ti < 4; ti++)
                #pragma unroll
                for(int r = 0; r < 4; r++)
                    v = fmaxf(v, __expf(fmaf(acc[ti][tj][r], sc[ti][r], bb[ti][r])));
            v = fmaxf(v, __shfl_xor(v, 16));
            v = fmaxf(v, __shfl_xor(v, 32));
            if(lane < 16)
                atomicMax(&colmaxk[(size_t)n*HW + js*256 + wave*64 + tj*16 + lane], fkey(v));
        }
    });
}

// ---------------- final: per-batch partial, then tiny reduce ----------------
__global__ __launch_bounds__(256) void kpart(const unsigned* __restrict__ colmaxk,
                                             float* __restrict__ part){
    __shared__ float red[256];
    const int t = threadIdx.x;
    const int n = blockIdx.x;
    float s = 0.f;
    for(int j = t; j < HW; j += 256) s += fdec(colmaxk[(size_t)n*HW + j]);
    red[t] = s; __syncthreads();
    for(int off = 128; off > 0; off >>= 1){
        if(t < off) red[t] += red[t+off];
        __syncthreads();
    }
    if(t == 0) part[n] = -logf(red[0]*(1.0f/HW) + EPSF);
}

__global__ __launch_bounds__(64) void kfin(const float* __restrict__ part,
                                           float* __restrict__ out){
    const int t = threadIdx.x;
    float v = (t < NBATCH) ? part[t] : 0.f;
    v += __shfl_xor(v, 1);
    v += __shfl_xor(v, 2);
    v += __shfl_xor(v, 4);
    if(t == 0) out[0] = v * (1.0f/NBATCH);
}

extern "C" void kernel_launch(void* const* d_in, const int* in_sizes, int n_in,
                              void* d_out, int out_size, void* d_ws, size_t ws_size,
                              hipStream_t stream){
    const float* x = (const float*)d_in[0];
    const float* y = (const float*)d_in[1];
    float* out = (float*)d_out;
    char* ws = (char*)d_ws;

    float* ymu = (float*)ws;
    size_t off = 1024;
    unsigned short* xF = (unsigned short*)(ws + off); off += (size_t)NBATCH*HW*CC*2;
    unsigned short* yF = (unsigned short*)(ws + off); off += (size_t)NBATCH*HW*CC*2 + (512<<10); // slack for tail prefetch
    unsigned* colmaxk  = (unsigned*)(ws + off);       off += (size_t)NBATCH*HW*4;
    float* part        = (float*)(ws + off);          off += 64;

    kmean<<<dim3(CC), dim3(256), 0, stream>>>(y, ymu);
    knorm<<<dim3(HW/64, NBATCH), dim3(256), 0, stream>>>(x, y, ymu, xF, yF, colmaxk);
    kccx<<<dim3(NBATCH*HW/64), dim3(256), 0, stream>>>(xF, yF, colmaxk);
    kpart<<<dim3(NBATCH), dim3(256), 0, stream>>>(colmaxk, part);
    kfin<<<dim3(1), dim3(64), 0, stream>>>(part, out);
}

// Round 5
// 314.516 us; speedup vs baseline: 1.6660x; 1.6660x over previous
//
#include <hip/hip_runtime.h>
#include <hip/hip_bf16.h>

#define HW 4096
#define CC 256
#define NBATCH 8
#define EPSF 1e-6f

typedef __attribute__((ext_vector_type(8))) short short8;
typedef __attribute__((ext_vector_type(4))) float floatx4;

// async global->LDS, 16B per lane (lds dst = uniform base + lane*16)
#define GLDS(g, l) __builtin_amdgcn_global_load_lds( \
    (const __attribute__((address_space(1))) void*)(const void*)(g), \
    (__attribute__((address_space(3))) void*)(void*)(l), 16, 0, 0)

// monotone float <-> unsigned key (order-preserving)
__device__ __forceinline__ unsigned fkey(float f){
    unsigned u = __float_as_uint(f);
    return (u & 0x80000000u) ? ~u : (u | 0x80000000u);
}
__device__ __forceinline__ float fdec(unsigned k){
    unsigned u = (k & 0x80000000u) ? (k ^ 0x80000000u) : ~k;
    return __uint_as_float(u);
}
__device__ __forceinline__ unsigned short f2bf(float f){
    unsigned u = __float_as_uint(f);
    u += 0x7FFFu + ((u >> 16) & 1);
    return (unsigned short)(u >> 16);
}

// ---------------- kernel 1: per-channel mean of y ----------------
__global__ __launch_bounds__(256) void kmean(const float* __restrict__ y,
                                             float* __restrict__ ymu){
    const int c = blockIdx.x;
    const int t = threadIdx.x;
    float s = 0.f;
    for(int n = 0; n < NBATCH; n++){
        const float* p = y + ((size_t)n*CC + c)*HW;
        for(int i = t; i < HW; i += 256) s += p[i];
    }
    __shared__ float red[256];
    red[t] = s; __syncthreads();
    for(int off = 128; off > 0; off >>= 1){
        if(t < off) red[t] += red[t+off];
        __syncthreads();
    }
    if(t == 0) ymu[c] = red[0] * (1.0f/((float)NBATCH*HW));
}

// ---- kernel 2: center, normalize over C, emit MFMA-fragment-major bf16 ----
// layout per batch: elem(i, c) at  (i>>4)*4096 + kt*512 + q*128 + (i&15)*8 + e
//   where c = kt*32 + q*8 + e.  Also inits dmink/rowsum/colmaxk.
#define TROW 264
__global__ __launch_bounds__(256) void knorm(const float* __restrict__ x,
                                             const float* __restrict__ y,
                                             const float* __restrict__ ymu,
                                             unsigned short* __restrict__ xF,
                                             unsigned short* __restrict__ yF,
                                             unsigned* __restrict__ dmink,
                                             float* __restrict__ rowsum,
                                             unsigned* __restrict__ colmaxk){
    __shared__ __align__(16) unsigned short tile[64*TROW];
    __shared__ float invn[64];
    __shared__ float partial[4][64];
    __shared__ float smu[CC];
    const int t   = threadIdx.x;
    const int hw0 = blockIdx.x * 64;
    const int n   = blockIdx.y;
    if(t < 64){
        size_t g = (size_t)n*HW + hw0 + t;
        dmink[g] = 0xFFFFFFFFu;
        rowsum[g] = 0.f;
        colmaxk[g] = 0u;
    }
    for(int c = t; c < CC; c += 256) smu[c] = ymu[c];
    const int hwl = t & 63;
    const int cch = t >> 6;
    for(int which = 0; which < 2; which++){
        const float* __restrict__ src = which ? y : x;
        unsigned short* __restrict__ dst = which ? yF : xF;
        __syncthreads();
        float ss = 0.f;
        for(int cc = 0; cc < 64; cc++){
            int c = cch*64 + cc;
            float v = src[((size_t)n*CC + c)*HW + hw0 + hwl] - smu[c];
            ss += v*v;
            tile[hwl*TROW + c] = f2bf(v);
        }
        partial[cch][hwl] = ss;
        __syncthreads();
        if(t < 64){
            float s = partial[0][t]+partial[1][t]+partial[2][t]+partial[3][t];
            invn[t] = rsqrtf(s);
        }
        __syncthreads();
        size_t base = (size_t)n*HW*CC + (size_t)(hw0 >> 4)*4096;
        #pragma unroll
        for(int v8 = 0; v8 < 8; v8++){
            int g   = v8*256 + t;          // 0..2047, unit = 8 halves
            int lit = g >> 9;
            int kt  = (g >> 6) & 7;
            int qq  = (g >> 4) & 3;
            int ll  = g & 15;
            int hr  = lit*16 + ll;
            float inv = invn[hr];
            const unsigned* lp = reinterpret_cast<const unsigned*>(&tile[hr*TROW + kt*32 + qq*8]);
            unsigned o[4];
            #pragma unroll
            for(int w2 = 0; w2 < 4; w2++){
                unsigned uu = lp[w2];
                float f0 = __uint_as_float((uu & 0xFFFFu) << 16) * inv;
                float f1 = __uint_as_float(uu & 0xFFFF0000u) * inv;
                o[w2] = (unsigned)f2bf(f0) | ((unsigned)f2bf(f1) << 16);
            }
            uint4 ov; ov.x=o[0]; ov.y=o[1]; ov.z=o[2]; ov.w=o[3];
            *reinterpret_cast<uint4*>(dst + base + (size_t)g*8) = ov;
        }
    }
}

// ---- sweep kernels: block = 256 i (4 waves x 64 i in regs) x 1024-j quarter.
// B staged via global_load_lds, double-buffered 16KB js-tiles (32 j x 256 c).
// MODE 0: dmin (atomicMin)   1: rowsum of w (atomicAdd)   2: colmax (atomicMax)
template<int MODE>
__global__ __launch_bounds__(256, 2) void ksweep(
        const unsigned short* __restrict__ xF,
        const unsigned short* __restrict__ yF,
        unsigned* __restrict__ dmink,
        float* __restrict__ rowsum,
        unsigned* __restrict__ colmaxk){
    __shared__ __align__(16) unsigned short Bs[2][8192];   // 2 x 16 KB
    const int t    = threadIdx.x;
    const int lane = t & 63;
    const int wave = t >> 6;
    const int q    = lane >> 4;
    const int l15  = lane & 15;
    const int bid  = blockIdx.x;
    const int n    = bid & 7;          // batch <-> XCD affinity
    const int rem  = bid >> 3;
    const int ip   = rem & 15;         // i-panel (256 rows)
    const int jq   = rem >> 4;         // j quarter (1024 cols)
    const size_t nbase = (size_t)n*HW*CC;
    const int iw   = ip*256 + wave*64; // this wave's 64 rows
    const unsigned short* Ax = xF + nbase + (size_t)(iw >> 4)*4096 + lane*8;
    const unsigned short* Yb = yF + nbase + (size_t)(jq*64)*4096;  // quarter region

    short8 af[4][8];
    #pragma unroll
    for(int ti = 0; ti < 4; ti++)
        #pragma unroll
        for(int kt = 0; kt < 8; kt++)
            af[ti][kt] = *reinterpret_cast<const short8*>(Ax + ti*4096 + kt*512);

    float sc[4][4], bb[4][4];
    if(MODE >= 1){
        #pragma unroll
        for(int ti = 0; ti < 4; ti++)
            #pragma unroll
            for(int r = 0; r < 4; r++){
                size_t g = (size_t)n*HW + iw + ti*16 + q*4 + r;
                float dm = fdec(dmink[g]);
                sc[ti][r] = 2.f / (dm + EPSF);
                if(MODE == 2) bb[ti][r] = 2.f - __logf(rowsum[g]);
            }
    }
    float racc[4][4];
    #pragma unroll
    for(int ti = 0; ti < 4; ti++)
        #pragma unroll
        for(int r = 0; r < 4; r++) racc[ti][r] = (MODE == 0) ? -3e38f : 0.f;

    // prologue: stage js=0 tile
    {
        const unsigned short* src = Yb;
        #pragma unroll
        for(int p = 0; p < 4; p++){
            int c = wave*4 + p;
            GLDS(src + c*512 + lane*8, &Bs[0][c*512]);
        }
    }
    __syncthreads();

    #pragma unroll 1
    for(int js = 0; js < 32; js++){
        // stage next tile (js=31 reads into slack; harmless)
        {
            const unsigned short* src = Yb + (size_t)(js+1)*8192;
            unsigned short* dstb = Bs[(js+1)&1];
            #pragma unroll
            for(int p = 0; p < 4; p++){
                int c = wave*4 + p;
                GLDS(src + c*512 + lane*8, &dstb[c*512]);
            }
        }
        const unsigned short* B = Bs[js&1];
        floatx4 acc[4][2];
        #pragma unroll
        for(int a = 0; a < 4; a++)
            #pragma unroll
            for(int b = 0; b < 2; b++) acc[a][b] = (floatx4){0.f,0.f,0.f,0.f};
        #pragma unroll
        for(int kt = 0; kt < 8; kt++){
            short8 b0 = *reinterpret_cast<const short8*>(B + kt*512 + lane*8);
            short8 b1 = *reinterpret_cast<const short8*>(B + 4096 + kt*512 + lane*8);
            #pragma unroll
            for(int ti = 0; ti < 4; ti++){
                acc[ti][0] = __builtin_amdgcn_mfma_f32_16x16x32_bf16(af[ti][kt], b0, acc[ti][0], 0, 0, 0);
                acc[ti][1] = __builtin_amdgcn_mfma_f32_16x16x32_bf16(af[ti][kt], b1, acc[ti][1], 0, 0, 0);
            }
        }
        if(MODE == 0){
            #pragma unroll
            for(int ti = 0; ti < 4; ti++)
                #pragma unroll
                for(int r = 0; r < 4; r++)
                    racc[ti][r] = fmaxf(racc[ti][r], fmaxf(acc[ti][0][r], acc[ti][1][r]));
        } else if(MODE == 1){
            #pragma unroll
            for(int ti = 0; ti < 4; ti++)
                #pragma unroll
                for(int r = 0; r < 4; r++)
                    racc[ti][r] += __expf(fmaf(acc[ti][0][r] - 1.f, sc[ti][r], 2.f))
                                 + __expf(fmaf(acc[ti][1][r] - 1.f, sc[ti][r], 2.f));
        } else {
            #pragma unroll
            for(int tj = 0; tj < 2; tj++){
                float a = -3e38f;
                #pragma unroll
                for(int ti = 0; ti < 4; ti++)
                    #pragma unroll
                    for(int r = 0; r < 4; r++)
                        a = fmaxf(a, fmaf(acc[ti][tj][r] - 1.f, sc[ti][r], bb[ti][r]));
                a = fmaxf(a, __shfl_xor(a, 16));
                a = fmaxf(a, __shfl_xor(a, 32));
                if(lane < 16)
                    atomicMax(&colmaxk[(size_t)n*HW + jq*1024 + js*32 + tj*16 + l15],
                              fkey(__expf(a)));
            }
        }
        __syncthreads();
    }

    if(MODE == 0){
        #pragma unroll
        for(int ti = 0; ti < 4; ti++)
            #pragma unroll
            for(int r = 0; r < 4; r++){
                float v = racc[ti][r];
                v = fmaxf(v, __shfl_xor(v, 1));
                v = fmaxf(v, __shfl_xor(v, 2));
                v = fmaxf(v, __shfl_xor(v, 4));
                v = fmaxf(v, __shfl_xor(v, 8));
                if(l15 == 0)
                    atomicMin(&dmink[(size_t)n*HW + iw + ti*16 + q*4 + r], fkey(1.f - v));
            }
    } else if(MODE == 1){
        #pragma unroll
        for(int ti = 0; ti < 4; ti++)
            #pragma unroll
            for(int r = 0; r < 4; r++){
                float v = racc[ti][r];
                v += __shfl_xor(v, 1);
                v += __shfl_xor(v, 2);
                v += __shfl_xor(v, 4);
                v += __shfl_xor(v, 8);
                if(l15 == 0)
                    atomicAdd(&rowsum[(size_t)n*HW + iw + ti*16 + q*4 + r], v);
            }
    }
}

// ---------------- final: per-batch partial, then tiny reduce ----------------
__global__ __launch_bounds__(256) void kpart(const unsigned* __restrict__ colmaxk,
                                             float* __restrict__ part){
    __shared__ float red[256];
    const int t = threadIdx.x;
    const int n = blockIdx.x;
    float s = 0.f;
    for(int j = t; j < HW; j += 256) s += fdec(colmaxk[(size_t)n*HW + j]);
    red[t] = s; __syncthreads();
    for(int off = 128; off > 0; off >>= 1){
        if(t < off) red[t] += red[t+off];
        __syncthreads();
    }
    if(t == 0) part[n] = -logf(red[0]*(1.0f/HW) + EPSF);
}

__global__ __launch_bounds__(64) void kfin(const float* __restrict__ part,
                                           float* __restrict__ out){
    const int t = threadIdx.x;
    float v = (t < NBATCH) ? part[t] : 0.f;
    v += __shfl_xor(v, 1);
    v += __shfl_xor(v, 2);
    v += __shfl_xor(v, 4);
    if(t == 0) out[0] = v * (1.0f/NBATCH);
}

extern "C" void kernel_launch(void* const* d_in, const int* in_sizes, int n_in,
                              void* d_out, int out_size, void* d_ws, size_t ws_size,
                              hipStream_t stream){
    const float* x = (const float*)d_in[0];
    const float* y = (const float*)d_in[1];
    float* out = (float*)d_out;
    char* ws = (char*)d_ws;

    float* ymu = (float*)ws;
    size_t off = 1024;
    unsigned short* xF = (unsigned short*)(ws + off); off += (size_t)NBATCH*HW*CC*2;
    unsigned short* yF = (unsigned short*)(ws + off); off += (size_t)NBATCH*HW*CC*2 + (512<<10); // tail-prefetch slack
    unsigned* dmink    = (unsigned*)(ws + off);       off += (size_t)NBATCH*HW*4;
    float* rowsum      = (float*)(ws + off);          off += (size_t)NBATCH*HW*4;
    unsigned* colmaxk  = (unsigned*)(ws + off);       off += (size_t)NBATCH*HW*4;
    float* part        = (float*)(ws + off);          off += 64;

    kmean<<<dim3(CC), dim3(256), 0, stream>>>(y, ymu);
    knorm<<<dim3(HW/64, NBATCH), dim3(256), 0, stream>>>(x, y, ymu, xF, yF,
                                                         dmink, rowsum, colmaxk);
    ksweep<0><<<dim3(512), dim3(256), 0, stream>>>(xF, yF, dmink, rowsum, colmaxk);
    ksweep<1><<<dim3(512), dim3(256), 0, stream>>>(xF, yF, dmink, rowsum, colmaxk);
    ksweep<2><<<dim3(512), dim3(256), 0, stream>>>(xF, yF, dmink, rowsum, colmaxk);
    kpart<<<dim3(NBATCH), dim3(256), 0, stream>>>(colmaxk, part);
    kfin<<<dim3(1), dim3(64), 0, stream>>>(part, out);
}

// Round 6
// 293.381 us; speedup vs baseline: 1.7860x; 1.0720x over previous
//
#include <hip/hip_runtime.h>
#include <hip/hip_bf16.h>

#define HW 4096
#define CC 256
#define NBATCH 8
#define EPSF 1e-6f

typedef __attribute__((ext_vector_type(4))) float floatx4;
typedef long long llong;

// async global->LDS, 16B per lane (lds dst = uniform base + lane*16)
#define GLDS(g, l) __builtin_amdgcn_global_load_lds( \
    (const __attribute__((address_space(1))) void*)(const void*)(g), \
    (__attribute__((address_space(3))) void*)(void*)(l), 16, 0, 0)

// monotone float <-> unsigned key (order-preserving)
__device__ __forceinline__ unsigned fkey(float f){
    unsigned u = __float_as_uint(f);
    return (u & 0x80000000u) ? ~u : (u | 0x80000000u);
}
__device__ __forceinline__ float fdec(unsigned k){
    unsigned u = (k & 0x80000000u) ? (k ^ 0x80000000u) : ~k;
    return __uint_as_float(u);
}
__device__ __forceinline__ unsigned short f2bf(float f){
    unsigned u = __float_as_uint(f);
    u += 0x7FFFu + ((u >> 16) & 1);
    return (unsigned short)(u >> 16);
}

// ---------------- kernel 1: per-channel mean of y ----------------
__global__ __launch_bounds__(256) void kmean(const float* __restrict__ y,
                                             float* __restrict__ ymu){
    const int c = blockIdx.x;
    const int t = threadIdx.x;
    float s = 0.f;
    for(int n = 0; n < NBATCH; n++){
        const float* p = y + ((size_t)n*CC + c)*HW;
        for(int i = t; i < HW; i += 256) s += p[i];
    }
    __shared__ float red[256];
    red[t] = s; __syncthreads();
    for(int off = 128; off > 0; off >>= 1){
        if(t < off) red[t] += red[t+off];
        __syncthreads();
    }
    if(t == 0) ymu[c] = red[0] * (1.0f/((float)NBATCH*HW));
}

// ---- kernel 2: center, normalize over C, emit MFMA-fragment-major FP8 ----
// fp8 layout per batch (1 MB): addr(i,c) = (i>>4)*4096 + kt*512 + q*128 + (i&15)*8 + e
//   where c = kt*32 + q*8 + e. Fragment load = base + lane*8 (8B/lane).
// Also inits dmink/rowsum/colmaxk.
#define TROW 264
__global__ __launch_bounds__(256) void knorm(const float* __restrict__ x,
                                             const float* __restrict__ y,
                                             const float* __restrict__ ymu,
                                             unsigned char* __restrict__ xF,
                                             unsigned char* __restrict__ yF,
                                             unsigned* __restrict__ dmink,
                                             float* __restrict__ rowsum,
                                             unsigned* __restrict__ colmaxk){
    __shared__ __align__(16) unsigned short tile[64*TROW];
    __shared__ float invn[64];
    __shared__ float partial[4][64];
    __shared__ float smu[CC];
    const int t   = threadIdx.x;
    const int hw0 = blockIdx.x * 64;
    const int n   = blockIdx.y;
    if(t < 64){
        size_t g = (size_t)n*HW + hw0 + t;
        dmink[g] = 0xFFFFFFFFu;
        rowsum[g] = 0.f;
        colmaxk[g] = 0u;
    }
    for(int c = t; c < CC; c += 256) smu[c] = ymu[c];
    const int hwl = t & 63;
    const int cch = t >> 6;
    for(int which = 0; which < 2; which++){
        const float* __restrict__ src = which ? y : x;
        unsigned char* __restrict__ dst = which ? yF : xF;
        __syncthreads();
        float ss = 0.f;
        for(int cc = 0; cc < 64; cc++){
            int c = cch*64 + cc;
            float v = src[((size_t)n*CC + c)*HW + hw0 + hwl] - smu[c];
            ss += v*v;
            tile[hwl*TROW + c] = f2bf(v);
        }
        partial[cch][hwl] = ss;
        __syncthreads();
        if(t < 64){
            float s = partial[0][t]+partial[1][t]+partial[2][t]+partial[3][t];
            invn[t] = rsqrtf(s);
        }
        __syncthreads();
        size_t base = ((size_t)n << 20) + (size_t)(hw0 >> 4)*4096;
        #pragma unroll
        for(int v4 = 0; v4 < 4; v4++){
            int g  = v4*256 + t;           // 0..1023, unit = 16 fp8 (2 rows x 8 c)
            int it = g >> 8;
            int kt = (g >> 5) & 7;
            int qq = (g >> 3) & 3;
            int u  = g & 7;
            int r0 = it*16 + u*2;
            unsigned w[4];
            #pragma unroll
            for(int rr = 0; rr < 2; rr++){
                int r = r0 + rr;
                float inv = invn[r];
                const unsigned* lp = reinterpret_cast<const unsigned*>(&tile[r*TROW + kt*32 + qq*8]);
                float f[8];
                #pragma unroll
                for(int w2 = 0; w2 < 4; w2++){
                    unsigned uu = lp[w2];
                    f[2*w2]   = __uint_as_float((uu & 0xFFFFu) << 16) * inv;
                    f[2*w2+1] = __uint_as_float(uu & 0xFFFF0000u) * inv;
                }
                unsigned wa = 0, wb = 0;
                wa = __builtin_amdgcn_cvt_pk_fp8_f32(f[0], f[1], wa, false);
                wa = __builtin_amdgcn_cvt_pk_fp8_f32(f[2], f[3], wa, true);
                wb = __builtin_amdgcn_cvt_pk_fp8_f32(f[4], f[5], wb, false);
                wb = __builtin_amdgcn_cvt_pk_fp8_f32(f[6], f[7], wb, true);
                w[2*rr] = wa; w[2*rr+1] = wb;
            }
            uint4 ov; ov.x=w[0]; ov.y=w[1]; ov.z=w[2]; ov.w=w[3];
            *reinterpret_cast<uint4*>(dst + base + it*4096 + kt*512 + qq*128 + u*16) = ov;
        }
    }
}

// ---- sweep kernels: block = 512 i (4 waves x 128 i in regs) x 512-j slice.
// B staged via global_load_lds, double-buffered 4KB tiles (16 j x 256 c fp8).
// MODE 0: dmin   1: rowsum of w   2: colmax of ccx
template<int MODE>
__global__ __launch_bounds__(256, 2) void ksweep(
        const unsigned char* __restrict__ xF,
        const unsigned char* __restrict__ yF,
        unsigned* __restrict__ dmink,
        float* __restrict__ rowsum,
        unsigned* __restrict__ colmaxk){
    __shared__ __align__(16) unsigned char Bs[2][4096];
    const int t    = threadIdx.x;
    const int lane = t & 63;
    const int wave = t >> 6;
    const int q    = lane >> 4;
    const int l15  = lane & 15;
    const int bid  = blockIdx.x;
    const int n    = bid & 7;          // batch <-> XCD affinity
    const int rem  = bid >> 3;
    const int ip   = rem & 7;          // i-panel (512 rows)
    const int jq   = rem >> 3;         // j slice (512 cols)
    const size_t nb8 = (size_t)n << 20;
    const size_t nbw = (size_t)n * HW;
    const int iw   = ip*512 + wave*128;   // this wave's 128 rows
    const unsigned char* Ax = xF + nb8 + (size_t)(iw >> 4)*4096 + (size_t)lane*8;
    const unsigned char* Yb = yF + nb8 + (size_t)jq*131072;   // 512 j * 256 B

    llong af[8][8];
    #pragma unroll
    for(int ti = 0; ti < 8; ti++)
        #pragma unroll
        for(int kt = 0; kt < 8; kt++)
            af[ti][kt] = *reinterpret_cast<const llong*>(Ax + ti*4096 + kt*512);

    float sc[8][4], bb[8][4];
    if(MODE >= 1){
        #pragma unroll
        for(int ti = 0; ti < 8; ti++)
            #pragma unroll
            for(int r = 0; r < 4; r++){
                size_t g = nbw + iw + ti*16 + q*4 + r;
                float dm = fdec(dmink[g]);
                sc[ti][r] = 2.f / (dm + EPSF);
                if(MODE == 2) bb[ti][r] = 2.f - __logf(rowsum[g]);
            }
    }
    float racc[8][4];
    #pragma unroll
    for(int ti = 0; ti < 8; ti++)
        #pragma unroll
        for(int r = 0; r < 4; r++) racc[ti][r] = (MODE == 0) ? -3e38f : 0.f;

    // prologue: stage js=0 tile (4KB; one 1KB chunk per wave)
    GLDS(Yb + wave*1024 + lane*16, &Bs[0][wave*1024]);
    __syncthreads();

    #pragma unroll 1
    for(int js = 0; js < 32; js++){
        // stage next tile (js=31 overreads 4KB into slack; harmless)
        GLDS(Yb + (js+1)*4096 + wave*1024 + lane*16, &Bs[(js+1)&1][wave*1024]);
        const unsigned char* B = Bs[js&1];
        floatx4 acc[8];
        #pragma unroll
        for(int a = 0; a < 8; a++) acc[a] = (floatx4){0.f,0.f,0.f,0.f};
        #pragma unroll
        for(int kt = 0; kt < 8; kt++){
            llong b = *reinterpret_cast<const llong*>(B + kt*512 + lane*8);
            #pragma unroll
            for(int ti = 0; ti < 8; ti++)
                acc[ti] = __builtin_amdgcn_mfma_f32_16x16x32_fp8_fp8(
                              af[ti][kt], b, acc[ti], 0, 0, 0);
        }
        if(MODE == 0){
            #pragma unroll
            for(int ti = 0; ti < 8; ti++)
                #pragma unroll
                for(int r = 0; r < 4; r++)
                    racc[ti][r] = fmaxf(racc[ti][r], acc[ti][r]);
        } else if(MODE == 1){
            #pragma unroll
            for(int ti = 0; ti < 8; ti++)
                #pragma unroll
                for(int r = 0; r < 4; r++)
                    racc[ti][r] += __expf(fmaf(acc[ti][r] - 1.f, sc[ti][r], 2.f));
        } else {
            float a = -3e38f;
            #pragma unroll
            for(int ti = 0; ti < 8; ti++)
                #pragma unroll
                for(int r = 0; r < 4; r++)
                    a = fmaxf(a, fmaf(acc[ti][r] - 1.f, sc[ti][r], bb[ti][r]));
            a = fmaxf(a, __shfl_xor(a, 16));
            a = fmaxf(a, __shfl_xor(a, 32));
            if(lane < 16)
                atomicMax(&colmaxk[nbw + jq*512 + js*16 + l15], fkey(__expf(a)));
        }
        __syncthreads();
    }

    if(MODE == 0){
        #pragma unroll
        for(int ti = 0; ti < 8; ti++)
            #pragma unroll
            for(int r = 0; r < 4; r++){
                float v = racc[ti][r];
                v = fmaxf(v, __shfl_xor(v, 1));
                v = fmaxf(v, __shfl_xor(v, 2));
                v = fmaxf(v, __shfl_xor(v, 4));
                v = fmaxf(v, __shfl_xor(v, 8));
                if(l15 == 0)
                    atomicMin(&dmink[nbw + iw + ti*16 + q*4 + r], fkey(1.f - v));
            }
    } else if(MODE == 1){
        #pragma unroll
        for(int ti = 0; ti < 8; ti++)
            #pragma unroll
            for(int r = 0; r < 4; r++){
                float v = racc[ti][r];
                v += __shfl_xor(v, 1);
                v += __shfl_xor(v, 2);
                v += __shfl_xor(v, 4);
                v += __shfl_xor(v, 8);
                if(l15 == 0)
                    atomicAdd(&rowsum[nbw + iw + ti*16 + q*4 + r], v);
            }
    }
}

// ---------------- final: per-batch partial, then tiny reduce ----------------
__global__ __launch_bounds__(256) void kpart(const unsigned* __restrict__ colmaxk,
                                             float* __restrict__ part){
    __shared__ float red[256];
    const int t = threadIdx.x;
    const int n = blockIdx.x;
    float s = 0.f;
    for(int j = t; j < HW; j += 256) s += fdec(colmaxk[(size_t)n*HW + j]);
    red[t] = s; __syncthreads();
    for(int off = 128; off > 0; off >>= 1){
        if(t < off) red[t] += red[t+off];
        __syncthreads();
    }
    if(t == 0) part[n] = -logf(red[0]*(1.0f/HW) + EPSF);
}

__global__ __launch_bounds__(64) void kfin(const float* __restrict__ part,
                                           float* __restrict__ out){
    const int t = threadIdx.x;
    float v = (t < NBATCH) ? part[t] : 0.f;
    v += __shfl_xor(v, 1);
    v += __shfl_xor(v, 2);
    v += __shfl_xor(v, 4);
    if(t == 0) out[0] = v * (1.0f/NBATCH);
}

extern "C" void kernel_launch(void* const* d_in, const int* in_sizes, int n_in,
                              void* d_out, int out_size, void* d_ws, size_t ws_size,
                              hipStream_t stream){
    const float* x = (const float*)d_in[0];
    const float* y = (const float*)d_in[1];
    float* out = (float*)d_out;
    char* ws = (char*)d_ws;

    float* ymu = (float*)ws;
    size_t off = 1024;
    unsigned char* xF = (unsigned char*)(ws + off); off += (size_t)NBATCH << 20;
    unsigned char* yF = (unsigned char*)(ws + off); off += ((size_t)NBATCH << 20) + (512<<10); // tail-prefetch slack
    unsigned* dmink   = (unsigned*)(ws + off);      off += (size_t)NBATCH*HW*4;
    float* rowsum     = (float*)(ws + off);         off += (size_t)NBATCH*HW*4;
    unsigned* colmaxk = (unsigned*)(ws + off);      off += (size_t)NBATCH*HW*4;
    float* part       = (float*)(ws + off);         off += 64;

    kmean<<<dim3(CC), dim3(256), 0, stream>>>(y, ymu);
    knorm<<<dim3(HW/64, NBATCH), dim3(256), 0, stream>>>(x, y, ymu, xF, yF,
                                                         dmink, rowsum, colmaxk);
    ksweep<0><<<dim3(512), dim3(256), 0, stream>>>(xF, yF, dmink, rowsum, colmaxk);
    ksweep<1><<<dim3(512), dim3(256), 0, stream>>>(xF, yF, dmink, rowsum, colmaxk);
    ksweep<2><<<dim3(512), dim3(256), 0, stream>>>(xF, yF, dmink, rowsum, colmaxk);
    kpart<<<dim3(NBATCH), dim3(256), 0, stream>>>(colmaxk, part);
    kfin<<<dim3(1), dim3(64), 0, stream>>>(part, out);
}